// Round 2
// baseline (222.240 us; speedup 1.0000x reference)
//
#include <hip/hip_runtime.h>

// KDE entropy loss, MI355X/gfx950 — fp8 fused GEMM, symmetric pairs once,
// wrapped-diagonal mapping. R9: revert to R7's single-barrier loop (R8's
// 2-phase/counted-vmcnt/setprio structure regressed: doubled lockstep
// barriers on a 2-block/CU grid). Keep R8's LDS colsums (WRITE_SIZE halved)
// and packed f32 adds. NEW: deferred epilogue (T15) — epilogue of tile k-1
// (32 quarter-rate v_exp_f32 + adds, ~320cy/wave) runs in iter k BEFORE the
// MFMA issue, so the VALU burst overlaps staging flight instead of
// serializing after the MFMA chain. Acc ping-pong with static naming via
// hand-unrolled pair loop; old set dies before new set is born (C=0 on the
// kbl==0 MFMA) so regalloc can coalesce -> no VGPR blowup.
// ws: [0,4MiB) Xn fp8 [16384][256]; [4MiB,+64KiB) density f32; then ticket u32.

#define NROWS 16384
#define KDIM 256            // bytes per fp8 row
#define NTILE 128
#define NT (NROWS / NTILE)  // 128 tile rows
#define NSTRIP 4
#define TOTAL_BLOCKS (NT * NSTRIP)  // 512 blocks of 512 thr = exactly 2 per CU

// sqrt(5 * log2(e)): folded into both operands -> sim scaled by 5*log2(e),
// so kernel = exp2(sim_scaled) = exp(5*sim).
#define SQRT_KLOG2E 2.68579577857f

#define CS_LDS_FLOATS (17 * NTILE)               // max nt = 17
#define SMEM_BYTES (65536 + CS_LDS_FLOATS * 4)   // 74240 B; 2 blocks/CU fits 160K

typedef int i32x4_t __attribute__((ext_vector_type(4)));
typedef int i32x8_t __attribute__((ext_vector_type(8)));
typedef float f32x2_t __attribute__((ext_vector_type(2)));
typedef float f32x16_t __attribute__((ext_vector_type(16)));
typedef __attribute__((address_space(1))) const void global_cvoid_t;
typedef __attribute__((address_space(3))) void lds_void_t;

#if __has_builtin(__builtin_amdgcn_exp2f)
#define EXP2(x) __builtin_amdgcn_exp2f(x)
#else
#define EXP2(x) exp2f(x)
#endif

union frag8 { i32x8_t v8; i32x4_t v4[2]; };

// One wave per row: sqrt(5log2e)/max(||x||,eps), fp8 e4m3 out; zero density+ticket.
__global__ __launch_bounds__(256)
void kde_normalize(const float* __restrict__ X, unsigned int* __restrict__ Xn8,
                   float* __restrict__ density, unsigned int* __restrict__ ticket) {
  const int wave = threadIdx.x >> 6;
  const int lane = threadIdx.x & 63;
  const int row = blockIdx.x * 4 + wave;
  const float4 v = ((const float4*)(X + (size_t)row * KDIM))[lane];
  float ss = v.x * v.x + v.y * v.y + v.z * v.z + v.w * v.w;
  ss += __shfl_xor(ss, 1);
  ss += __shfl_xor(ss, 2);
  ss += __shfl_xor(ss, 4);
  ss += __shfl_xor(ss, 8);
  ss += __shfl_xor(ss, 16);
  ss += __shfl_xor(ss, 32);
  const float scale = SQRT_KLOG2E / fmaxf(sqrtf(ss), 1e-12f);
  int p = 0;
  p = __builtin_amdgcn_cvt_pk_fp8_f32(v.x * scale, v.y * scale, p, false);
  p = __builtin_amdgcn_cvt_pk_fp8_f32(v.z * scale, v.w * scale, p, true);
  Xn8[(size_t)row * 64 + lane] = (unsigned int)p;
  if (threadIdx.x < 4) density[blockIdx.x * 4 + threadIdx.x] = 0.0f;
  if (blockIdx.x == 0 && threadIdx.x == 0) *ticket = 0u;
}

// Block (bi, s): row tile bi; J = (bi+t) mod 128 for t in [s*16, s*16+16)
// (+ t=64 for s==0, bi<64). Each unordered tile pair once. 8 waves 4x2 over
// 128x128; wave = 32x64 = 1x2 MFMA 32x32x64 fp8 (scale=1 -> exact e4m3).
// A in registers (32 VGPR); B double-buffers in 64 KB LDS; 1 barrier/iter
// (full drain — loads issued at iter top have a whole iteration to land).
// Deferred epilogue: EPI(k-1) placed before MFMA(k) issue.
__global__ __launch_bounds__(512, 4)
void kde_gemm(const unsigned char* __restrict__ Xn8, float* __restrict__ density,
              unsigned int* __restrict__ ticket, float* __restrict__ out) {
  extern __shared__ char smem[];
  char* buf0 = smem;           // 32 KB
  char* buf1 = smem + 32768;   // 32 KB
  float* cs_lds = (float*)(smem + 65536);  // [nt][128] colsum accumulators

  const int tid = threadIdx.x;
  const int wave = tid >> 6;   // 0..7
  const int lane = tid & 63;
  const int wr = wave >> 1;    // row quarter 0..3 (32 rows each)
  const int wc = wave & 1;     // col half 0..1 (64 cols each)
  const int m32 = lane & 31;
  const int h = lane >> 5;
  const int bi = blockIdx.x;
  const int s = blockIdx.y;
  const int t0 = s * 16;
  const int nt = (s == 0 && bi < NT / 2) ? 17 : 16;
  const char* Xb = (const char*)Xn8;

  // Chunk c = rt*8 + kb*2 + hh: lane holds M[rt*32+m32][kb*64+h*32+hh*16 ..+15]
#define STAGE(base_row, dst)                                                      \
  for (int c = wave; c < 32; c += 8) {                                            \
    const int rt = c >> 3, kb = (c >> 1) & 3, hh = c & 1;                         \
    const size_t gofs =                                                           \
        (size_t)((base_row) + rt * 32 + m32) * KDIM + kb * 64 + h * 32 + hh * 16; \
    __builtin_amdgcn_global_load_lds((global_cvoid_t*)(Xb + gofs),                \
                                     (lds_void_t*)((dst) + c * 1024), 16, 0, 0);  \
  }

  // Epilogue for tile index KI (acc set ACC): e = exp2(sim_scaled) = exp(5*sim).
  // Rowsums in regs across k; colsums into LDS (ds atomics: lgkm path).
  // C/D: col = m32, row = (r&3) + 8*(r>>2) + 4*h.
#define EPI(ACC, KI)                                                              \
  {                                                                               \
    const int tt_ = ((KI) == 16) ? 64 : (t0 + (KI));                              \
    _Pragma("unroll")                                                             \
    for (int j = 0; j < 2; j++) {                                                 \
      f32x2_t csj = (f32x2_t)0.0f;                                                \
      _Pragma("unroll")                                                           \
      for (int r2 = 0; r2 < 8; r2++) {                                            \
        f32x2_t e;                                                                \
        e.x = EXP2(ACC[j][2 * r2]);                                               \
        e.y = EXP2(ACC[j][2 * r2 + 1]);                                           \
        rs2[r2] += e; /* v_pk_add_f32 */                                          \
        csj += e;                                                                 \
      }                                                                           \
      if (tt_ != 0) { /* diagonal tile (t=0): rowsum only */                      \
        float v_ = csj.x + csj.y;                                                 \
        v_ += __shfl_xor(v_, 32); /* combine h halves -> 32 rows */               \
        if (h == 0)                                                               \
          atomicAdd(&cs_lds[(KI) * NTILE + wc * 64 + j * 32 + m32], v_);          \
      }                                                                           \
    }                                                                             \
  }

  // One J-tile iteration. PAR = K&1 (static). ACCW written (born at kbl==0
  // via C=0 — no zero-init, and after EPI reads ACCR so live ranges are
  // disjoint -> coalescible). DO_EPI is a compile-time literal.
#define BODY(K, PAR, ACCW, ACCR, DO_EPI, KPREV)                                   \
  {                                                                               \
    char* rbuf_ = (PAR) ? buf0 : buf1; /* B(K): landed at last barrier */         \
    char* sbuf_ = (PAR) ? buf1 : buf0; /* free since last barrier */              \
    if ((K) + 1 < nt) {                                                           \
      const int tn_ = ((K) + 1 == 16) ? 64 : (t0 + (K) + 1);                      \
      STAGE(((bi + tn_) & (NT - 1)) * NTILE, sbuf_);                              \
    }                                                                             \
    if (DO_EPI) EPI(ACCR, KPREV);                                                 \
    _Pragma("unroll")                                                             \
    for (int kbl = 0; kbl < 4; ++kbl) {                                           \
      frag8 bf[2];                                                                \
      _Pragma("unroll")                                                           \
      for (int j = 0; j < 2; j++) {                                               \
        const char* pb = rbuf_ + ((wc * 2 + j) * 8 + kbl * 2) * 1024 + lane * 16; \
        bf[j].v4[0] = *(const i32x4_t*)pb;                                        \
        bf[j].v4[1] = *(const i32x4_t*)(pb + 1024);                               \
      }                                                                           \
      _Pragma("unroll")                                                           \
      for (int j = 0; j < 2; j++)                                                 \
        ACCW[j] = __builtin_amdgcn_mfma_scale_f32_32x32x64_f8f6f4(                \
            areg[kbl].v8, bf[j].v8,                                               \
            (kbl == 0) ? (f32x16_t)0.0f : ACCW[j], 0, 0, 0, 127, 0, 127);         \
    }                                                                             \
    __syncthreads(); /* full drain: B(K+1) landed; all waves done with rbuf_ */   \
  }

  // Zero colsum accumulators (visible after the first __syncthreads).
  for (int i = tid; i < nt * NTILE; i += 512) cs_lds[i] = 0.0f;

  STAGE(bi * NTILE, buf0);                      // A tile -> buf0
  STAGE(((bi + t0) & (NT - 1)) * NTILE, buf1);  // B(0)   -> buf1
  __syncthreads();  // both landed (vmcnt drained at barrier)

  // A fragments -> registers: this wave's 32 rows, full K (32 VGPRs).
  frag8 areg[4];
#pragma unroll
  for (int kb = 0; kb < 4; kb++) {
    const char* pa = buf0 + (wr * 8 + kb * 2) * 1024 + lane * 16;
    areg[kb].v4[0] = *(const i32x4_t*)pa;
    areg[kb].v4[1] = *(const i32x4_t*)(pa + 1024);
  }
  __syncthreads();  // all waves done reading A from buf0

  f32x2_t rs2[8];
#pragma unroll
  for (int r = 0; r < 8; r++) rs2[r] = (f32x2_t)0.0f;

  f32x16_t accA[2], accB[2];

  // Iter 0: compute into accA, no epilogue yet.
  BODY(0, 0, accA, accA, false, 0);

  // Pair loop: static ping-pong (rule #20: no runtime acc indexing).
  int k = 1;
  for (; k + 1 < nt; k += 2) {
    BODY(k, 1, accB, accA, true, k - 1);
    BODY(k + 1, 0, accA, accB, true, k);
  }
  if (k < nt) {  // nt even (16): one leftover odd iter
    BODY(k, 1, accB, accA, true, k - 1);
    EPI(accB, k);
  } else {       // nt odd (17): pairs covered everything
    EPI(accA, nt - 1);
  }

  // Row epilogue: reduce over 32 cols (m32), scatter; 2 atomics/row (wc=0,1).
#pragma unroll
  for (int r = 0; r < 16; r++) {
    float v = rs2[r >> 1][r & 1];
    v += __shfl_xor(v, 1);
    v += __shfl_xor(v, 2);
    v += __shfl_xor(v, 4);
    v += __shfl_xor(v, 8);
    v += __shfl_xor(v, 16);
    if (m32 == 0) {
      const int row = bi * NTILE + wr * 32 + (r & 3) + 8 * (r >> 2) + 4 * h;
      atomicAdd(&density[row], v);
    }
  }

  // Colsum flush: lgkm drained by __syncthreads -> all waves' ds_adds done.
  __syncthreads();
  for (int idx = tid; idx < nt * NTILE; idx += 512) {
    const int kk = idx >> 7;
    const int tt = (kk == 16) ? 64 : (t0 + kk);
    if (tt == 0) continue;  // diagonal tile: never written
    const int JJ = (bi + tt) & (NT - 1);
    atomicAdd(&density[JJ * NTILE + (idx & 127)], cs_lds[idx]);
  }
#undef STAGE
#undef EPI
#undef BODY

  // Ticket: last finished block computes the entropy (saves 2 launches).
  __syncthreads();  // all atomics issued & drained (vmcnt(0) at barrier)
  if (tid == 0) {
    __threadfence();
    ((volatile unsigned int*)smem)[0] = atomicAdd(ticket, 1u);
  }
  __syncthreads();
  if (((volatile unsigned int*)smem)[0] == TOTAL_BLOCKS - 1) {
    __threadfence();
    float ssum = 0.0f;
    for (int i = tid; i < NROWS; i += 512) {
      const float d = __hip_atomic_load(&density[i], __ATOMIC_RELAXED,
                                        __HIP_MEMORY_SCOPE_AGENT);
      ssum += logf(d + 1e-9f);
    }
    ssum += __shfl_xor(ssum, 1);
    ssum += __shfl_xor(ssum, 2);
    ssum += __shfl_xor(ssum, 4);
    ssum += __shfl_xor(ssum, 8);
    ssum += __shfl_xor(ssum, 16);
    ssum += __shfl_xor(ssum, 32);
    float* red = ((float*)smem) + 16;
    if (lane == 0) red[wave] = ssum;
    __syncthreads();
    if (tid == 0) {
      float tot = 0.0f;
      for (int w = 0; w < 8; w++) tot += red[w];
      out[0] = -tot / (float)NROWS;
    }
  }
}

extern "C" void kernel_launch(void* const* d_in, const int* in_sizes, int n_in,
                              void* d_out, int out_size, void* d_ws, size_t ws_size,
                              hipStream_t stream) {
  const float* X = (const float*)d_in[0];
  float* out = (float*)d_out;
  char* ws = (char*)d_ws;
  unsigned int* Xn8 = (unsigned int*)ws;
  float* density = (float*)(ws + (size_t)NROWS * KDIM);
  unsigned int* ticket = (unsigned int*)(density + NROWS);

  hipFuncSetAttribute((const void*)kde_gemm,
                      hipFuncAttributeMaxDynamicSharedMemorySize, SMEM_BYTES);

  kde_normalize<<<NROWS / 4, 256, 0, stream>>>(X, Xn8, density, ticket);
  kde_gemm<<<dim3(NT, NSTRIP), 512, SMEM_BYTES, stream>>>(
      (const unsigned char*)ws, density, ticket, out);
}

// Round 3
// 130.605 us; speedup vs baseline: 1.7016x; 1.7016x over previous
//
#include <hip/hip_runtime.h>

// KDE entropy loss, MI355X/gfx950 — fp8 fused GEMM, symmetric pairs once,
// wrapped-diagonal mapping. R10 = R7 (best measured: gemm 68.2us) with ONE
// change, validated mechanically in R8: per-iter colsum global atomics
// (whose L2 acks the per-iter barrier's vmcnt(0) drain waited on) replaced
// by LDS accumulators (ds_add, lgkm path) flushed once after the loop; plus
// packed f32 epilogue adds. R8's 2-phase barriers and R9's deferred-epilogue
// acc ping-pong (spilled: 450MB scratch traffic) are both reverted.
// ws: [0,4MiB) Xn fp8 [16384][256]; [4MiB,+64KiB) density f32; then ticket u32.

#define NROWS 16384
#define KDIM 256            // bytes per fp8 row
#define NTILE 128
#define NT (NROWS / NTILE)  // 128 tile rows
#define NSTRIP 4
#define TOTAL_BLOCKS (NT * NSTRIP)  // 512 blocks of 512 thr = exactly 2 per CU

// sqrt(5 * log2(e)): folded into both operands -> sim scaled by 5*log2(e),
// so kernel = exp2(sim_scaled) = exp(5*sim).
#define SQRT_KLOG2E 2.68579577857f

#define CS_LDS_FLOATS (17 * NTILE)               // max nt = 17
#define SMEM_BYTES (65536 + CS_LDS_FLOATS * 4)   // 74240 B; 2 blocks/CU fits 160K

typedef int i32x4_t __attribute__((ext_vector_type(4)));
typedef int i32x8_t __attribute__((ext_vector_type(8)));
typedef float f32x2_t __attribute__((ext_vector_type(2)));
typedef float f32x16_t __attribute__((ext_vector_type(16)));
typedef __attribute__((address_space(1))) const void global_cvoid_t;
typedef __attribute__((address_space(3))) void lds_void_t;

#if __has_builtin(__builtin_amdgcn_exp2f)
#define EXP2(x) __builtin_amdgcn_exp2f(x)
#else
#define EXP2(x) exp2f(x)
#endif

union frag8 { i32x8_t v8; i32x4_t v4[2]; };

// One wave per row: sqrt(5log2e)/max(||x||,eps), fp8 e4m3 out; zero density+ticket.
__global__ __launch_bounds__(256)
void kde_normalize(const float* __restrict__ X, unsigned int* __restrict__ Xn8,
                   float* __restrict__ density, unsigned int* __restrict__ ticket) {
  const int wave = threadIdx.x >> 6;
  const int lane = threadIdx.x & 63;
  const int row = blockIdx.x * 4 + wave;
  const float4 v = ((const float4*)(X + (size_t)row * KDIM))[lane];
  float ss = v.x * v.x + v.y * v.y + v.z * v.z + v.w * v.w;
  ss += __shfl_xor(ss, 1);
  ss += __shfl_xor(ss, 2);
  ss += __shfl_xor(ss, 4);
  ss += __shfl_xor(ss, 8);
  ss += __shfl_xor(ss, 16);
  ss += __shfl_xor(ss, 32);
  const float scale = SQRT_KLOG2E / fmaxf(sqrtf(ss), 1e-12f);
  int p = 0;
  p = __builtin_amdgcn_cvt_pk_fp8_f32(v.x * scale, v.y * scale, p, false);
  p = __builtin_amdgcn_cvt_pk_fp8_f32(v.z * scale, v.w * scale, p, true);
  Xn8[(size_t)row * 64 + lane] = (unsigned int)p;
  if (threadIdx.x < 4) density[blockIdx.x * 4 + threadIdx.x] = 0.0f;
  if (blockIdx.x == 0 && threadIdx.x == 0) *ticket = 0u;
}

// Block (bi, s): row tile bi; J = (bi+t) mod 128 for t in [s*16, s*16+16)
// (+ t=64 for s==0, bi<64 — dispatched first so the 17-iter blocks start
// earliest). Each unordered tile pair once. 8 waves 4x2 over 128x128; wave =
// 32x64 = 1x2 MFMA 32x32x64 fp8 (scale=1 -> exact e4m3). A in registers
// (32 VGPR); B double-buffers in 64 KB LDS; 1 barrier/iter. No global vmem
// ops inside the loop: colsums accumulate in cs_lds (ds atomics, lgkm path —
// NOT part of the barrier's vmcnt drain), flushed once after the loop.
__global__ __launch_bounds__(512, 4)
void kde_gemm(const unsigned char* __restrict__ Xn8, float* __restrict__ density,
              unsigned int* __restrict__ ticket, float* __restrict__ out) {
  extern __shared__ char smem[];
  char* buf0 = smem;           // 32 KB
  char* buf1 = smem + 32768;   // 32 KB
  float* cs_lds = (float*)(smem + 65536);  // [nt][128] colsum accumulators

  const int tid = threadIdx.x;
  const int wave = tid >> 6;   // 0..7
  const int lane = tid & 63;
  const int wr = wave >> 1;    // row quarter 0..3 (32 rows each)
  const int wc = wave & 1;     // col half 0..1 (64 cols each)
  const int m32 = lane & 31;
  const int h = lane >> 5;
  const int bi = blockIdx.x;
  const int s = blockIdx.y;
  const int t0 = s * 16;
  const int nt = (s == 0 && bi < NT / 2) ? 17 : 16;
  const char* Xb = (const char*)Xn8;

  // Chunk c = rt*8 + kb*2 + hh: lane holds M[rt*32+m32][kb*64+h*32+hh*16 ..+15]
  // (identical layout to R5's verified kernel; 4 chunks per wave).
#define STAGE(base_row, dst)                                                      \
  for (int c = wave; c < 32; c += 8) {                                            \
    const int rt = c >> 3, kb = (c >> 1) & 3, hh = c & 1;                         \
    const size_t gofs =                                                           \
        (size_t)((base_row) + rt * 32 + m32) * KDIM + kb * 64 + h * 32 + hh * 16; \
    __builtin_amdgcn_global_load_lds((global_cvoid_t*)(Xb + gofs),                \
                                     (lds_void_t*)((dst) + c * 1024), 16, 0, 0);  \
  }

  // Zero colsum accumulators (visible after the first __syncthreads).
  for (int i = tid; i < nt * NTILE; i += 512) cs_lds[i] = 0.0f;

  STAGE(bi * NTILE, buf0);                      // A tile -> buf0
  STAGE(((bi + t0) & (NT - 1)) * NTILE, buf1);  // B(0)   -> buf1
  __syncthreads();  // both landed (vmcnt drained at barrier) + cs_lds zeros

  // A fragments -> registers: this wave's 32 rows, full K (32 VGPRs).
  frag8 areg[4];
#pragma unroll
  for (int kb = 0; kb < 4; kb++) {
    const char* pa = buf0 + (wr * 8 + kb * 2) * 1024 + lane * 16;
    areg[kb].v4[0] = *(const i32x4_t*)pa;
    areg[kb].v4[1] = *(const i32x4_t*)(pa + 1024);
  }
  __syncthreads();  // all waves done reading A from buf0

  f32x2_t rs2[8];
#pragma unroll
  for (int r = 0; r < 8; r++) rs2[r] = (f32x2_t)0.0f;

  for (int k = 0; k < nt; ++k) {
    const int t = (k == 16) ? 64 : (t0 + k);
    char* rbuf = (k & 1) ? buf0 : buf1;  // B(k): landed at last barrier
    char* sbuf = (k & 1) ? buf1 : buf0;  // free since last barrier

    if (k + 1 < nt) {
      const int tn = (k + 1 == 16) ? 64 : (t0 + k + 1);
      STAGE(((bi + tn) & (NT - 1)) * NTILE, sbuf);
    }

    f32x16_t acc[2];
#pragma unroll
    for (int j = 0; j < 2; j++) acc[j] = (f32x16_t)0.0f;

#pragma unroll
    for (int kb = 0; kb < 4; ++kb) {
      frag8 bf[2];
#pragma unroll
      for (int j = 0; j < 2; j++) {
        const char* pb = rbuf + ((wc * 2 + j) * 8 + kb * 2) * 1024 + lane * 16;
        bf[j].v4[0] = *(const i32x4_t*)pb;
        bf[j].v4[1] = *(const i32x4_t*)(pb + 1024);
      }
#pragma unroll
      for (int j = 0; j < 2; j++)
        acc[j] = __builtin_amdgcn_mfma_scale_f32_32x32x64_f8f6f4(
            areg[kb].v8, bf[j].v8, acc[j], 0, 0, 0, 127, 0, 127);
    }

    // Epilogue: e = exp2(sim_scaled) = exp(5*sim). Rowsums in regs across k
    // (packed adds); colsums into cs_lds via ds atomics — lgkm path, so the
    // barrier's vmcnt drain no longer waits on L2 atomic acks each iter.
    // C/D: col = m32, row = (r&3) + 8*(r>>2) + 4*h.
#pragma unroll
    for (int j = 0; j < 2; j++) {
      f32x2_t csj = (f32x2_t)0.0f;
#pragma unroll
      for (int r2 = 0; r2 < 8; r2++) {
        f32x2_t e;
        e.x = EXP2(acc[j][2 * r2]);
        e.y = EXP2(acc[j][2 * r2 + 1]);
        rs2[r2] += e;  // v_pk_add_f32
        csj += e;
      }
      if (t != 0) {  // diagonal tile (t=0): rowsum only
        float v = csj.x + csj.y;
        v += __shfl_xor(v, 32);  // combine h halves -> 32 rows
        if (h == 0)  // 4 LDS atomics/col (wr=0..3 waves)
          atomicAdd(&cs_lds[k * NTILE + wc * 64 + j * 32 + m32], v);
      }
    }

    __syncthreads();  // B(k+1) landed; all waves done reading rbuf
  }

  // Row epilogue: reduce over 32 cols (m32), scatter; 2 atomics/row (wc=0,1).
#pragma unroll
  for (int r = 0; r < 16; r++) {
    float v = rs2[r >> 1][r & 1];
    v += __shfl_xor(v, 1);
    v += __shfl_xor(v, 2);
    v += __shfl_xor(v, 4);
    v += __shfl_xor(v, 8);
    v += __shfl_xor(v, 16);
    if (m32 == 0) {
      const int row = bi * NTILE + wr * 32 + (r & 3) + 8 * (r >> 2) + 4 * h;
      atomicAdd(&density[row], v);
    }
  }

  // Colsum flush: lgkm drained by __syncthreads -> all waves' ds_adds done.
  __syncthreads();
  for (int idx = tid; idx < nt * NTILE; idx += 512) {
    const int kk = idx >> 7;
    const int tt = (kk == 16) ? 64 : (t0 + kk);
    if (tt == 0) continue;  // diagonal tile: never written
    const int JJ = (bi + tt) & (NT - 1);
    atomicAdd(&density[JJ * NTILE + (idx & 127)], cs_lds[idx]);
  }
#undef STAGE

  // Ticket: last finished block computes the entropy (saves 2 launches).
  __syncthreads();  // all atomics issued & drained (vmcnt(0) at barrier)
  if (tid == 0) {
    __threadfence();
    ((volatile unsigned int*)smem)[0] = atomicAdd(ticket, 1u);
  }
  __syncthreads();
  if (((volatile unsigned int*)smem)[0] == TOTAL_BLOCKS - 1) {
    __threadfence();
    float ssum = 0.0f;
    for (int i = tid; i < NROWS; i += 512) {
      const float d = __hip_atomic_load(&density[i], __ATOMIC_RELAXED,
                                        __HIP_MEMORY_SCOPE_AGENT);
      ssum += logf(d + 1e-9f);
    }
    ssum += __shfl_xor(ssum, 1);
    ssum += __shfl_xor(ssum, 2);
    ssum += __shfl_xor(ssum, 4);
    ssum += __shfl_xor(ssum, 8);
    ssum += __shfl_xor(ssum, 16);
    ssum += __shfl_xor(ssum, 32);
    float* red = ((float*)smem) + 16;
    if (lane == 0) red[wave] = ssum;
    __syncthreads();
    if (tid == 0) {
      float tot = 0.0f;
      for (int w = 0; w < 8; w++) tot += red[w];
      out[0] = -tot / (float)NROWS;
    }
  }
}

extern "C" void kernel_launch(void* const* d_in, const int* in_sizes, int n_in,
                              void* d_out, int out_size, void* d_ws, size_t ws_size,
                              hipStream_t stream) {
  const float* X = (const float*)d_in[0];
  float* out = (float*)d_out;
  char* ws = (char*)d_ws;
  unsigned int* Xn8 = (unsigned int*)ws;
  float* density = (float*)(ws + (size_t)NROWS * KDIM);
  unsigned int* ticket = (unsigned int*)(density + NROWS);

  hipFuncSetAttribute((const void*)kde_gemm,
                      hipFuncAttributeMaxDynamicSharedMemorySize, SMEM_BYTES);

  kde_normalize<<<NROWS / 4, 256, 0, stream>>>(X, Xn8, density, ticket);
  kde_gemm<<<dim3(NT, NSTRIP), 512, SMEM_BYTES, stream>>>(
      (const unsigned char*)ws, density, ticket, out);
}

// Round 4
// 124.745 us; speedup vs baseline: 1.7816x; 1.0470x over previous
//
#include <hip/hip_runtime.h>

// KDE entropy loss, MI355X/gfx950 — fp8 fused GEMM, symmetric pairs once,
// wrapped-diagonal mapping. R11 = R7's exact skeleton (best measured: gemm
// 68.2us — in-loop global colsum atomics are FREE per R8/R10 ablations;
// LDS-colsum variants regressed) + within-iteration software pipelining:
// j=0 MFMA chain first, then j=1 chain hand-interleaved with epilogue
// slices of acc0 (1 MFMA + 4 exp2 + pk-adds per step), j=0 colsum atomic
// fired mid-chain. Zero extra liveness (both acc halves already live in
// R7), zero extra barriers. Only acc1's epilogue (~half the VALU burst)
// remains outside an MFMA shadow.
// ws: [0,4MiB) Xn fp8 [16384][256]; [4MiB,+64KiB) density f32; then ticket u32.

#define NROWS 16384
#define KDIM 256            // bytes per fp8 row
#define NTILE 128
#define NT (NROWS / NTILE)  // 128 tile rows
#define NSTRIP 4
#define TOTAL_BLOCKS (NT * NSTRIP)  // 512 blocks of 512 thr = exactly 2 per CU

// sqrt(5 * log2(e)): folded into both operands -> sim scaled by 5*log2(e),
// so kernel = exp2(sim_scaled) = exp(5*sim).
#define SQRT_KLOG2E 2.68579577857f

typedef int i32x4_t __attribute__((ext_vector_type(4)));
typedef int i32x8_t __attribute__((ext_vector_type(8)));
typedef float f32x2_t __attribute__((ext_vector_type(2)));
typedef float f32x16_t __attribute__((ext_vector_type(16)));
typedef __attribute__((address_space(1))) const void global_cvoid_t;
typedef __attribute__((address_space(3))) void lds_void_t;

#if __has_builtin(__builtin_amdgcn_exp2f)
#define EXP2(x) __builtin_amdgcn_exp2f(x)
#else
#define EXP2(x) exp2f(x)
#endif

union frag8 { i32x8_t v8; i32x4_t v4[2]; };

// One wave per row: sqrt(5log2e)/max(||x||,eps), fp8 e4m3 out; zero density+ticket.
__global__ __launch_bounds__(256)
void kde_normalize(const float* __restrict__ X, unsigned int* __restrict__ Xn8,
                   float* __restrict__ density, unsigned int* __restrict__ ticket) {
  const int wave = threadIdx.x >> 6;
  const int lane = threadIdx.x & 63;
  const int row = blockIdx.x * 4 + wave;
  const float4 v = ((const float4*)(X + (size_t)row * KDIM))[lane];
  float ss = v.x * v.x + v.y * v.y + v.z * v.z + v.w * v.w;
  ss += __shfl_xor(ss, 1);
  ss += __shfl_xor(ss, 2);
  ss += __shfl_xor(ss, 4);
  ss += __shfl_xor(ss, 8);
  ss += __shfl_xor(ss, 16);
  ss += __shfl_xor(ss, 32);
  const float scale = SQRT_KLOG2E / fmaxf(sqrtf(ss), 1e-12f);
  int p = 0;
  p = __builtin_amdgcn_cvt_pk_fp8_f32(v.x * scale, v.y * scale, p, false);
  p = __builtin_amdgcn_cvt_pk_fp8_f32(v.z * scale, v.w * scale, p, true);
  Xn8[(size_t)row * 64 + lane] = (unsigned int)p;
  if (threadIdx.x < 4) density[blockIdx.x * 4 + threadIdx.x] = 0.0f;
  if (blockIdx.x == 0 && threadIdx.x == 0) *ticket = 0u;
}

// Block (bi, s): row tile bi; J = (bi+t) mod 128 for t in [s*16, s*16+16)
// (+ t=64 for s==0, bi<64 — dispatched first so the 17-iter blocks start
// earliest). Each unordered tile pair once. 8 waves 4x2 over 128x128; wave =
// 32x64 = 1x2 MFMA 32x32x64 fp8 (scale=1 -> exact e4m3). A in registers
// (32 VGPR); B double-buffers in 64 KB LDS; 1 barrier/iter; in-loop global
// colsum atomics (measured free — hidden under the iteration).
__global__ __launch_bounds__(512, 4)
void kde_gemm(const unsigned char* __restrict__ Xn8, float* __restrict__ density,
              unsigned int* __restrict__ ticket, float* __restrict__ out) {
  extern __shared__ char smem[];
  char* buf0 = smem;           // 32 KB
  char* buf1 = smem + 32768;   // 32 KB

  const int tid = threadIdx.x;
  const int wave = tid >> 6;   // 0..7
  const int lane = tid & 63;
  const int wr = wave >> 1;    // row quarter 0..3 (32 rows each)
  const int wc = wave & 1;     // col half 0..1 (64 cols each)
  const int m32 = lane & 31;
  const int h = lane >> 5;
  const int bi = blockIdx.x;
  const int s = blockIdx.y;
  const int t0 = s * 16;
  const int nt = (s == 0 && bi < NT / 2) ? 17 : 16;
  const char* Xb = (const char*)Xn8;

  // Chunk c = rt*8 + kb*2 + hh: lane holds M[rt*32+m32][kb*64+h*32+hh*16 ..+15]
#define STAGE(base_row, dst)                                                      \
  for (int c = wave; c < 32; c += 8) {                                            \
    const int rt = c >> 3, kb = (c >> 1) & 3, hh = c & 1;                         \
    const size_t gofs =                                                           \
        (size_t)((base_row) + rt * 32 + m32) * KDIM + kb * 64 + h * 32 + hh * 16; \
    __builtin_amdgcn_global_load_lds((global_cvoid_t*)(Xb + gofs),                \
                                     (lds_void_t*)((dst) + c * 1024), 16, 0, 0);  \
  }

  STAGE(bi * NTILE, buf0);                      // A tile -> buf0
  STAGE(((bi + t0) & (NT - 1)) * NTILE, buf1);  // B(0)   -> buf1
  __syncthreads();  // both landed (vmcnt drained at barrier)

  // A fragments -> registers: this wave's 32 rows, full K (32 VGPRs).
  frag8 areg[4];
#pragma unroll
  for (int kb = 0; kb < 4; kb++) {
    const char* pa = buf0 + (wr * 8 + kb * 2) * 1024 + lane * 16;
    areg[kb].v4[0] = *(const i32x4_t*)pa;
    areg[kb].v4[1] = *(const i32x4_t*)(pa + 1024);
  }
  __syncthreads();  // all waves done reading A from buf0

  f32x2_t rs2[8];
#pragma unroll
  for (int r = 0; r < 8; r++) rs2[r] = (f32x2_t)0.0f;

  for (int k = 0; k < nt; ++k) {
    const int t = (k == 16) ? 64 : (t0 + k);
    const int J = (bi + t) & (NT - 1);
    char* rbuf = (k & 1) ? buf0 : buf1;  // B(k): landed at last barrier
    char* sbuf = (k & 1) ? buf1 : buf0;  // free since last barrier

    if (k + 1 < nt) {
      const int tn = (k + 1 == 16) ? 64 : (t0 + k + 1);
      STAGE(((bi + tn) & (NT - 1)) * NTILE, sbuf);
    }

    f32x16_t acc0 = (f32x16_t)0.0f;
    f32x16_t acc1 = (f32x16_t)0.0f;

    // ---- j=0 MFMA chain (reads overlap chain via compiler lgkmcnt) ----
#pragma unroll
    for (int kb = 0; kb < 4; ++kb) {
      frag8 bf;
      const char* pb = rbuf + ((wc * 2 + 0) * 8 + kb * 2) * 1024 + lane * 16;
      bf.v4[0] = *(const i32x4_t*)pb;
      bf.v4[1] = *(const i32x4_t*)(pb + 1024);
      acc0 = __builtin_amdgcn_mfma_scale_f32_32x32x64_f8f6f4(
          areg[kb].v8, bf.v8, acc0, 0, 0, 0, 127, 0, 127);
    }

    // ---- j=1 chain, hand-interleaved with acc0's epilogue slices ----
    // Per kb step: 1 MFMA (+2 ds_reads) + 4 exp2 + 2 pk-adds of acc0 —
    // the VALU/trans work fills the ~68cy MFMA pipe shadow.
    f32x2_t cs0 = (f32x2_t)0.0f;
#pragma unroll
    for (int kb = 0; kb < 4; ++kb) {
      frag8 bf;
      const char* pb = rbuf + ((wc * 2 + 1) * 8 + kb * 2) * 1024 + lane * 16;
      bf.v4[0] = *(const i32x4_t*)pb;
      bf.v4[1] = *(const i32x4_t*)(pb + 1024);
      acc1 = __builtin_amdgcn_mfma_scale_f32_32x32x64_f8f6f4(
          areg[kb].v8, bf.v8, acc1, 0, 0, 0, 127, 0, 127);
#pragma unroll
      for (int r2 = 2 * kb; r2 < 2 * kb + 2; ++r2) {
        f32x2_t e;
        e.x = EXP2(acc0[2 * r2]);
        e.y = EXP2(acc0[2 * r2 + 1]);
        rs2[r2] += e;  // v_pk_add_f32
        cs0 += e;
      }
    }

    // j=0 colsum: reduce + global atomic fired mid-iteration (ack hidden
    // until the barrier's vmcnt drain, with the acc1 epilogue in between).
    if (t != 0) {
      float v = cs0.x + cs0.y;
      v += __shfl_xor(v, 32);  // combine h halves -> 32 rows
      if (h == 0) atomicAdd(&density[J * NTILE + wc * 64 + m32], v);
    }

    // ---- acc1 epilogue (exposed; ~half the original burst) ----
    f32x2_t cs1 = (f32x2_t)0.0f;
#pragma unroll
    for (int r2 = 0; r2 < 8; ++r2) {
      f32x2_t e;
      e.x = EXP2(acc1[2 * r2]);
      e.y = EXP2(acc1[2 * r2 + 1]);
      rs2[r2] += e;
      cs1 += e;
    }
    if (t != 0) {
      float v = cs1.x + cs1.y;
      v += __shfl_xor(v, 32);
      if (h == 0) atomicAdd(&density[J * NTILE + wc * 64 + 32 + m32], v);
    }

    __syncthreads();  // B(k+1) landed; all waves done reading rbuf
  }

  // Row epilogue: reduce over 32 cols (m32), scatter; 2 atomics/row (wc=0,1).
#pragma unroll
  for (int r = 0; r < 16; r++) {
    float v = rs2[r >> 1][r & 1];
    v += __shfl_xor(v, 1);
    v += __shfl_xor(v, 2);
    v += __shfl_xor(v, 4);
    v += __shfl_xor(v, 8);
    v += __shfl_xor(v, 16);
    if (m32 == 0) {
      const int row = bi * NTILE + wr * 32 + (r & 3) + 8 * (r >> 2) + 4 * h;
      atomicAdd(&density[row], v);
    }
  }
#undef STAGE

  // Ticket: last finished block computes the entropy (saves 2 launches).
  __syncthreads();  // all waves' atomics issued & drained (vmcnt(0) at barrier)
  if (tid == 0) {
    __threadfence();
    ((volatile unsigned int*)smem)[0] = atomicAdd(ticket, 1u);
  }
  __syncthreads();
  if (((volatile unsigned int*)smem)[0] == TOTAL_BLOCKS - 1) {
    __threadfence();
    float ssum = 0.0f;
    for (int i = tid; i < NROWS; i += 512) {
      const float d = __hip_atomic_load(&density[i], __ATOMIC_RELAXED,
                                        __HIP_MEMORY_SCOPE_AGENT);
      ssum += logf(d + 1e-9f);
    }
    ssum += __shfl_xor(ssum, 1);
    ssum += __shfl_xor(ssum, 2);
    ssum += __shfl_xor(ssum, 4);
    ssum += __shfl_xor(ssum, 8);
    ssum += __shfl_xor(ssum, 16);
    ssum += __shfl_xor(ssum, 32);
    float* red = ((float*)smem) + 16;
    if (lane == 0) red[wave] = ssum;
    __syncthreads();
    if (tid == 0) {
      float tot = 0.0f;
      for (int w = 0; w < 8; w++) tot += red[w];
      out[0] = -tot / (float)NROWS;
    }
  }
}

extern "C" void kernel_launch(void* const* d_in, const int* in_sizes, int n_in,
                              void* d_out, int out_size, void* d_ws, size_t ws_size,
                              hipStream_t stream) {
  const float* X = (const float*)d_in[0];
  float* out = (float*)d_out;
  char* ws = (char*)d_ws;
  unsigned int* Xn8 = (unsigned int*)ws;
  float* density = (float*)(ws + (size_t)NROWS * KDIM);
  unsigned int* ticket = (unsigned int*)(density + NROWS);

  hipFuncSetAttribute((const void*)kde_gemm,
                      hipFuncAttributeMaxDynamicSharedMemorySize, 65536);

  kde_normalize<<<NROWS / 4, 256, 0, stream>>>(X, Xn8, density, ticket);
  kde_gemm<<<dim3(NT, NSTRIP), 512, 65536, stream>>>((const unsigned char*)ws,
                                                     density, ticket, out);
}